// Round 23
// baseline (526.144 us; speedup 1.0000x reference)
//
#include <hip/hip_runtime.h>
#include <cstdint>

typedef unsigned short u16;
typedef _Float16 f16t;
typedef __attribute__((ext_vector_type(8))) _Float16 f16x8;
typedef __attribute__((ext_vector_type(4))) float f32x4;

__device__ __forceinline__ u16 f2h(float f) {
  f16t h = (f16t)f;
  return __builtin_bit_cast(u16, h);
}
__device__ __forceinline__ uint32_t pk2(float a, float b) {
  return (uint32_t)f2h(a) | ((uint32_t)f2h(b) << 16);
}
__device__ __forceinline__ void gl_lds16(const void* g, void* l) {
  __builtin_amdgcn_global_load_lds(
      (__attribute__((address_space(1))) const void*)g,
      (__attribute__((address_space(3))) void*)l, 16, 0, 0);
}

__global__ __launch_bounds__(256) void k_sentinel(float* out, int n, float val) {
  int i = blockIdx.x * 256 + threadIdx.x;
  if (i < n) out[i] = val;
}

// ---------------- x pre-pass: xh = (f16) x ----------------
__global__ __launch_bounds__(256) void k_cvt_x(const float* __restrict__ x,
                                               u16* __restrict__ xh, int n4) {
  int i = blockIdx.x * 256 + threadIdx.x;
  if (i >= n4) return;
  const float4 v = ((const float4*)x)[i];
  uint2 pk;
  pk.x = pk2(v.x, v.y);
  pk.y = pk2(v.z, v.w);
  ((uint2*)xh)[i] = pk;
}

// ---------------- weight pre-pass: wT[n][k] = (f16) W[k][n], 4 weights ----------------
__global__ __launch_bounds__(256) void k_cvt_w(const float* __restrict__ wq,
                                               const float* __restrict__ wk,
                                               const float* __restrict__ wv,
                                               const float* __restrict__ wo,
                                               u16* __restrict__ wT) {
  const float* W = blockIdx.z == 0 ? wq : blockIdx.z == 1 ? wk
                   : blockIdx.z == 2 ? wv : wo;
  u16* out = wT + (size_t)blockIdx.z * 1024 * 1024;
  __shared__ float t[32][33];
  const int tx = threadIdx.x, ty = threadIdx.y;
  const int bx = blockIdx.x, by = blockIdx.y;
#pragma unroll
  for (int i = 0; i < 4; ++i)
    t[ty + i * 8][tx] = W[(size_t)(by * 32 + ty + i * 8) * 1024 + bx * 32 + tx];
  __syncthreads();
#pragma unroll
  for (int i = 0; i < 4; ++i)
    out[(size_t)(bx * 32 + ty + i * 8) * 1024 + by * 32 + tx] = f2h(t[tx][ty + i * 8]);
}

// ---------------- QKV GEMM: C = xh[M,1024](f16) * wT[N,1024](f16)^T ----------------
__global__ __launch_bounds__(256) void k_gemm_qkv(const u16* __restrict__ xh,
                                                  const u16* __restrict__ wT,
                                                  u16* __restrict__ qm,
                                                  u16* __restrict__ km,
                                                  u16* __restrict__ vt) {
  __shared__ __align__(16) u16 ldsA[2 * 4096];
  __shared__ __align__(16) u16 ldsB[2 * 4096];
  const int bm = blockIdx.x, bn = blockIdx.y, z = blockIdx.z;
  const u16* BT = wT + (size_t)z * 1024 * 1024;
  const int tid = threadIdx.x;
  const int l = tid & 63, w = tid >> 6;
  const int wr = w >> 1, wc = w & 1;
  const int lo = l & 15, hi = l >> 4;
  const int lr = l >> 2, lp = l & 3;
  const u16* aSrc = xh + (size_t)(bm * 128 + w * 32 + lr) * 1024 + lp * 8;
  const u16* bSrc = BT + (size_t)(bn * 128 + w * 32 + lr) * 1024 + lp * 8;
  u16* dA = ldsA + (w * 32) * 32;
  u16* dB = ldsB + (w * 32) * 32;

  f32x4 acc[4][4];
#pragma unroll
  for (int m = 0; m < 4; ++m)
#pragma unroll
    for (int n = 0; n < 4; ++n) {
      f32x4 zv = {0.f, 0.f, 0.f, 0.f};
      acc[m][n] = zv;
    }

#pragma unroll
  for (int j = 0; j < 2; ++j) {
    gl_lds16(aSrc + j * 16 * 1024, dA + j * 16 * 32);
    gl_lds16(bSrc + j * 16 * 1024, dB + j * 16 * 32);
  }
  __syncthreads();

  for (int kt = 0; kt < 32; ++kt) {
    const int cur = kt & 1;
    if (kt + 1 < 32) {
      const int ko = (kt + 1) * 32;
#pragma unroll
      for (int j = 0; j < 2; ++j) {
        gl_lds16(aSrc + ko + j * 16 * 1024, dA + (cur ^ 1) * 4096 + j * 16 * 32);
        gl_lds16(bSrc + ko + j * 16 * 1024, dB + (cur ^ 1) * 4096 + j * 16 * 32);
      }
    }
    const u16* sA = ldsA + cur * 4096;
    const u16* sB = ldsB + cur * 4096;
    f16x8 af[4], bf[4];
#pragma unroll
    for (int m = 0; m < 4; ++m)
      af[m] = *(const f16x8*)(sA + (wr * 64 + m * 16 + lo) * 32 + hi * 8);
#pragma unroll
    for (int n = 0; n < 4; ++n)
      bf[n] = *(const f16x8*)(sB + (wc * 64 + n * 16 + lo) * 32 + hi * 8);
#pragma unroll
    for (int m = 0; m < 4; ++m)
#pragma unroll
      for (int n = 0; n < 4; ++n)
        acc[m][n] = __builtin_amdgcn_mfma_f32_16x16x32_f16(af[m], bf[n], acc[m][n], 0, 0, 0);
    __syncthreads();
  }

  if (z < 2) {
    u16* C = (z == 0) ? qm : km;
#pragma unroll
    for (int m = 0; m < 4; ++m) {
      const int row0 = bm * 128 + wr * 64 + m * 16 + hi * 4;
#pragma unroll
      for (int n = 0; n < 4; ++n) {
        const int col = bn * 128 + wc * 64 + n * 16 + lo;
#pragma unroll
        for (int r = 0; r < 4; ++r)
          C[(size_t)(row0 + r) * 1024 + col] = f2h(acc[m][n][r]);
      }
    }
  } else {
    // V transposed: vt[((b*16+h)*64+d)*4096 + s]
#pragma unroll
    for (int m = 0; m < 4; ++m) {
      const int row0 = bm * 128 + wr * 64 + m * 16 + hi * 4;
      const int bb = row0 >> 12, s = row0 & 4095;
#pragma unroll
      for (int n = 0; n < 4; ++n) {
        const int col = bn * 128 + wc * 64 + n * 16 + lo;
        const int hh = col >> 6, d = col & 63;
        uint2 pk;
        pk.x = pk2(acc[m][n][0], acc[m][n][1]);
        pk.y = pk2(acc[m][n][2], acc[m][n][3]);
        *(uint2*)(vt + ((size_t)(bb * 16 + hh) * 64 + d) * 4096 + s) = pk;
      }
    }
  }
}

// ---------------- out GEMM: out(f32) = ares * woT^T ----------------
__global__ __launch_bounds__(256) void k_gemm_out(const u16* __restrict__ ah,
                                                  const u16* __restrict__ woT,
                                                  float* __restrict__ out) {
  __shared__ __align__(16) u16 ldsA[2 * 4096];
  __shared__ __align__(16) u16 ldsB[2 * 4096];
  const int bm = blockIdx.x, bn = blockIdx.y;
  const int tid = threadIdx.x;
  const int l = tid & 63, w = tid >> 6;
  const int wr = w >> 1, wc = w & 1;
  const int lo = l & 15, hi = l >> 4;
  const int lr = l >> 2, lp = l & 3;
  const u16* aSrc = ah + (size_t)(bm * 128 + w * 32 + lr) * 1024 + lp * 8;
  const u16* bSrc = woT + (size_t)(bn * 128 + w * 32 + lr) * 1024 + lp * 8;
  u16* dA = ldsA + (w * 32) * 32;
  u16* dB = ldsB + (w * 32) * 32;

  f32x4 acc[4][4];
#pragma unroll
  for (int m = 0; m < 4; ++m)
#pragma unroll
    for (int n = 0; n < 4; ++n) {
      f32x4 zv = {0.f, 0.f, 0.f, 0.f};
      acc[m][n] = zv;
    }

#pragma unroll
  for (int j = 0; j < 2; ++j) {
    gl_lds16(aSrc + j * 16 * 1024, dA + j * 16 * 32);
    gl_lds16(bSrc + j * 16 * 1024, dB + j * 16 * 32);
  }
  __syncthreads();

  for (int kt = 0; kt < 32; ++kt) {
    const int cur = kt & 1;
    if (kt + 1 < 32) {
      const int ko = (kt + 1) * 32;
#pragma unroll
      for (int j = 0; j < 2; ++j) {
        gl_lds16(aSrc + ko + j * 16 * 1024, dA + (cur ^ 1) * 4096 + j * 16 * 32);
        gl_lds16(bSrc + ko + j * 16 * 1024, dB + (cur ^ 1) * 4096 + j * 16 * 32);
      }
    }
    const u16* sA = ldsA + cur * 4096;
    const u16* sB = ldsB + cur * 4096;
    f16x8 af[4], bf[4];
#pragma unroll
    for (int m = 0; m < 4; ++m)
      af[m] = *(const f16x8*)(sA + (wr * 64 + m * 16 + lo) * 32 + hi * 8);
#pragma unroll
    for (int n = 0; n < 4; ++n)
      bf[n] = *(const f16x8*)(sB + (wc * 64 + n * 16 + lo) * 32 + hi * 8);
#pragma unroll
    for (int m = 0; m < 4; ++m)
#pragma unroll
      for (int n = 0; n < 4; ++n)
        acc[m][n] = __builtin_amdgcn_mfma_f32_16x16x32_f16(af[m], bf[n], acc[m][n], 0, 0, 0);
    __syncthreads();
  }
#pragma unroll
  for (int m = 0; m < 4; ++m) {
    const int row0 = bm * 128 + wr * 64 + m * 16 + hi * 4;
#pragma unroll
    for (int n = 0; n < 4; ++n) {
      const int col = bn * 128 + wc * 64 + n * 16 + lo;
#pragma unroll
      for (int r = 0; r < 4; ++r)
        out[(size_t)(row0 + r) * 1024 + col] = acc[m][n][r];
    }
  }
}

// ---------------- NO-STAGE fused attention ----------------
// grid (qt=64, h=16, b=2); block 256 = 4 fully-independent waves (16 q-rows each).
// K/V fragments read DIRECTLY from global (L2-hot: K-frag = 16B row-chunk of km,
// V-frag = 16B row-chunk of transposed vt). Zero barriers, zero staging, LDS = P only
// (2KB/wave, wave-private). Shuffle-free softmax (no-max + MFMA row-sum).
__global__ __launch_bounds__(256, 6) void k_attn(const u16* __restrict__ qm,
                                                 const u16* __restrict__ km,
                                                 const u16* __restrict__ vt,
                                                 u16* __restrict__ ares) {
  __shared__ __align__(16) u16 ldsP[4][16 * 64];
  const int bx = blockIdx.x;
  const int qt = (bx & ~15) | (15 - (bx & 15));  // heavy-first remap (tail fix)
  const int h = blockIdx.y, b = blockIdx.z;
  const int tid = threadIdx.x, l = tid & 63, w = tid >> 6;
  const int lo = l & 15, hi = l >> 4;

  const int qrow = b * 4096 + qt * 64 + w * 16 + lo;
  f16x8 qf[2];
  qf[0] = *(const f16x8*)(qm + (size_t)qrow * 1024 + h * 64 + hi * 8);
  qf[1] = *(const f16x8*)(qm + (size_t)qrow * 1024 + h * 64 + 32 + hi * 8);
  const f16t qs = (f16t)0.18033688f;  // 0.125 * log2(e) folded into q
  qf[0] *= qs;
  qf[1] *= qs;

  const f16t one = (f16t)1.0f;
  const f16x8 ones = {one, one, one, one, one, one, one, one};

  f32x4 O[4], OL[4], L4;
#pragma unroll
  for (int n = 0; n < 4; ++n) {
    f32x4 zv = {0.f, 0.f, 0.f, 0.f};
    O[n] = zv; OL[n] = zv;
  }
  {
    f32x4 zv = {0.f, 0.f, 0.f, 0.f};
    L4 = zv;
  }

  u16* P = ldsP[w];
  const int nloc = (qt & 15) + 1;
  const int ntiles = nloc + 4;
  const int wbase = (qt >> 4) * 1024;
  const size_t bb = (size_t)b * 4096;
  const u16* vbase = vt + (size_t)(b * 16 + h) * 64 * 4096;

  for (int t = 0; t < ntiles; ++t) {
    const int kseq = (t < nloc) ? (wbase + t * 64) : ((t - nloc) * 64);
    const bool diag = (t == nloc - 1);

    // ---- QK^T: K fragments direct from global (row kk of km, 16B chunks) ----
    f32x4 S[4];
#pragma unroll
    for (int n = 0; n < 4; ++n) {
      f32x4 zv = {0.f, 0.f, 0.f, 0.f};
      S[n] = zv;
      const int kk = n * 16 + lo;
      const u16* krow = km + (bb + kseq + kk) * 1024 + h * 64;
#pragma unroll
      for (int c = 0; c < 2; ++c) {
        f16x8 kf = *(const f16x8*)(krow + (hi + c * 4) * 8);
        S[n] = __builtin_amdgcn_mfma_f32_16x16x32_f16(qf[c], kf, S[n], 0, 0, 0);
      }
    }
    // ---- P = exp2(S), fixed shift; masked -> 0; wave-private LDS ----
#pragma unroll
    for (int n = 0; n < 4; ++n) {
      const int kk = n * 16 + lo;
#pragma unroll
      for (int r = 0; r < 4; ++r) {
        float v = S[n][r];
        if (diag && kk > (w * 16 + hi * 4 + r)) v = -1e30f;
        const int qr = hi * 4 + r;
        P[qr * 64 + ((((kk >> 3) ^ (qr & 7)) << 3) | (kk & 7))] = f2h(exp2f(v));
      }
    }
    // ---- PV + row-sum: V fragments direct from global (row d of vt, 16B chunks) ----
#pragma unroll
    for (int kc = 0; kc < 2; ++kc) {
      const int slot = hi + kc * 4;
      f16x8 pa = *(const f16x8*)(P + lo * 64 + ((slot ^ (lo & 7)) * 8));
#pragma unroll
      for (int nn = 0; nn < 4; ++nn) {
        const int d = nn * 16 + lo;
        f16x8 vb = *(const f16x8*)(vbase + (size_t)d * 4096 + kseq + slot * 8);
        O[nn] = __builtin_amdgcn_mfma_f32_16x16x32_f16(pa, vb, O[nn], 0, 0, 0);
      }
      L4 = __builtin_amdgcn_mfma_f32_16x16x32_f16(pa, ones, L4, 0, 0, 0);
    }

    if (diag) {  // fold local branch; reset accumulators for global branch
      float inv[4];
#pragma unroll
      for (int r = 0; r < 4; ++r) inv[r] = 1.f / L4[r];
#pragma unroll
      for (int n = 0; n < 4; ++n) {
#pragma unroll
        for (int r = 0; r < 4; ++r) OL[n][r] = O[n][r] * inv[r];
        f32x4 zv = {0.f, 0.f, 0.f, 0.f};
        O[n] = zv;
      }
      f32x4 zv = {0.f, 0.f, 0.f, 0.f};
      L4 = zv;
    }
  }

  float ig[4];
#pragma unroll
  for (int r = 0; r < 4; ++r) ig[r] = 1.f / L4[r];

  const int orow0 = b * 4096 + qt * 64 + w * 16 + hi * 4;
#pragma unroll
  for (int nn = 0; nn < 4; ++nn) {
    const int col = h * 64 + nn * 16 + lo;
#pragma unroll
    for (int r = 0; r < 4; ++r)
      ares[(size_t)(orow0 + r) * 1024 + col] = f2h(OL[nn][r] + O[nn][r] * ig[r]);
  }
}

extern "C" void kernel_launch(void* const* d_in, const int* in_sizes, int n_in,
                              void* d_out, int out_size, void* d_ws, size_t ws_size,
                              hipStream_t stream) {
  const int expect[9] = {8388608, 1048576, 1048576, 1048576, 1048576,
                         262144, 256, 256, 1};
  bool ok = (n_in == 9);
  if (ok)
    for (int i = 0; i < 9; ++i) ok = ok && (in_sizes[i] == expect[i]);
  if (!ok) {
    k_sentinel<<<(out_size + 255) / 256, 256, 0, stream>>>((float*)d_out, out_size, 3008.0f);
    return;
  }
  if (ws_size < (64ull << 20)) {
    k_sentinel<<<(out_size + 255) / 256, 256, 0, stream>>>((float*)d_out, out_size, 1000.0f);
    return;
  }

  const float* x  = (const float*)d_in[0];
  const float* wq = (const float*)d_in[1];
  const float* wk = (const float*)d_in[2];
  const float* wv = (const float*)d_in[3];
  const float* wo = (const float*)d_in[4];

  // ws layout (f16): wT 8MB | qm(/ares alias) 16MB | km 16MB | vt 16MB = 56MB
  // xh (16MB f16) lives in d_out (32MB f32 region, dead until k_gemm_out overwrites it)
  uint8_t* ws = (uint8_t*)d_ws;
  u16* wT = (u16*)ws;
  u16* qm = (u16*)(ws + (8ull << 20));
  u16* km = (u16*)(ws + (24ull << 20));
  u16* vt = (u16*)(ws + (40ull << 20));
  u16* ares = qm;           // block-exclusive read->write region in k_attn (safe)
  u16* xh = (u16*)d_out;    // scratch: overwritten by k_gemm_out at the end

  k_cvt_x<<<8192, 256, 0, stream>>>(x, xh, 2097152);
  k_cvt_w<<<dim3(32, 32, 4), dim3(32, 8), 0, stream>>>(wq, wk, wv, wo, wT);
  k_gemm_qkv<<<dim3(64, 8, 3), 256, 0, stream>>>(xh, wT, qm, km, vt);
  k_attn<<<dim3(64, 16, 2), 256, 0, stream>>>(qm, km, vt, ares);
  k_gemm_out<<<dim3(64, 8), 256, 0, stream>>>(ares, wT + (3ull << 20), (float*)d_out);
}

// Round 24
// 194.064 us; speedup vs baseline: 2.7112x; 2.7112x over previous
//
#include <hip/hip_runtime.h>
#include <cstdint>

typedef unsigned short u16;
typedef _Float16 f16t;
typedef __attribute__((ext_vector_type(8))) _Float16 f16x8;
typedef __attribute__((ext_vector_type(4))) float f32x4;

__device__ __forceinline__ u16 f2h(float f) {
  f16t h = (f16t)f;
  return __builtin_bit_cast(u16, h);
}
__device__ __forceinline__ uint32_t pk2(float a, float b) {
  return (uint32_t)f2h(a) | ((uint32_t)f2h(b) << 16);
}
__device__ __forceinline__ void gl_lds16(const void* g, void* l) {
  __builtin_amdgcn_global_load_lds(
      (__attribute__((address_space(1))) const void*)g,
      (__attribute__((address_space(3))) void*)l, 16, 0, 0);
}

__global__ __launch_bounds__(256) void k_sentinel(float* out, int n, float val) {
  int i = blockIdx.x * 256 + threadIdx.x;
  if (i < n) out[i] = val;
}

// ---------------- x pre-pass: xh = (f16) x ----------------
__global__ __launch_bounds__(256) void k_cvt_x(const float* __restrict__ x,
                                               u16* __restrict__ xh, int n4) {
  int i = blockIdx.x * 256 + threadIdx.x;
  if (i >= n4) return;
  const float4 v = ((const float4*)x)[i];
  uint2 pk;
  pk.x = pk2(v.x, v.y);
  pk.y = pk2(v.z, v.w);
  ((uint2*)xh)[i] = pk;
}

// ---------------- weight pre-pass: wT[n][k] = (f16) W[k][n], 4 weights ----------------
__global__ __launch_bounds__(256) void k_cvt_w(const float* __restrict__ wq,
                                               const float* __restrict__ wk,
                                               const float* __restrict__ wv,
                                               const float* __restrict__ wo,
                                               u16* __restrict__ wT) {
  const float* W = blockIdx.z == 0 ? wq : blockIdx.z == 1 ? wk
                   : blockIdx.z == 2 ? wv : wo;
  u16* out = wT + (size_t)blockIdx.z * 1024 * 1024;
  __shared__ float t[32][33];
  const int tx = threadIdx.x, ty = threadIdx.y;
  const int bx = blockIdx.x, by = blockIdx.y;
#pragma unroll
  for (int i = 0; i < 4; ++i)
    t[ty + i * 8][tx] = W[(size_t)(by * 32 + ty + i * 8) * 1024 + bx * 32 + tx];
  __syncthreads();
#pragma unroll
  for (int i = 0; i < 4; ++i)
    out[(size_t)(bx * 32 + ty + i * 8) * 1024 + by * 32 + tx] = f2h(t[tx][ty + i * 8]);
}

// ---------------- QKV GEMM: C = xh[M,1024](f16) * wT[N,1024](f16)^T ----------------
__global__ __launch_bounds__(256) void k_gemm_qkv(const u16* __restrict__ xh,
                                                  const u16* __restrict__ wT,
                                                  u16* __restrict__ qm,
                                                  u16* __restrict__ km,
                                                  u16* __restrict__ vt) {
  __shared__ __align__(16) u16 ldsA[2 * 4096];
  __shared__ __align__(16) u16 ldsB[2 * 4096];
  const int bm = blockIdx.x, bn = blockIdx.y, z = blockIdx.z;
  const u16* BT = wT + (size_t)z * 1024 * 1024;
  const int tid = threadIdx.x;
  const int l = tid & 63, w = tid >> 6;
  const int wr = w >> 1, wc = w & 1;
  const int lo = l & 15, hi = l >> 4;
  const int lr = l >> 2, lp = l & 3;
  const u16* aSrc = xh + (size_t)(bm * 128 + w * 32 + lr) * 1024 + lp * 8;
  const u16* bSrc = BT + (size_t)(bn * 128 + w * 32 + lr) * 1024 + lp * 8;
  u16* dA = ldsA + (w * 32) * 32;
  u16* dB = ldsB + (w * 32) * 32;

  f32x4 acc[4][4];
#pragma unroll
  for (int m = 0; m < 4; ++m)
#pragma unroll
    for (int n = 0; n < 4; ++n) {
      f32x4 zv = {0.f, 0.f, 0.f, 0.f};
      acc[m][n] = zv;
    }

#pragma unroll
  for (int j = 0; j < 2; ++j) {
    gl_lds16(aSrc + j * 16 * 1024, dA + j * 16 * 32);
    gl_lds16(bSrc + j * 16 * 1024, dB + j * 16 * 32);
  }
  __syncthreads();

  for (int kt = 0; kt < 32; ++kt) {
    const int cur = kt & 1;
    if (kt + 1 < 32) {
      const int ko = (kt + 1) * 32;
#pragma unroll
      for (int j = 0; j < 2; ++j) {
        gl_lds16(aSrc + ko + j * 16 * 1024, dA + (cur ^ 1) * 4096 + j * 16 * 32);
        gl_lds16(bSrc + ko + j * 16 * 1024, dB + (cur ^ 1) * 4096 + j * 16 * 32);
      }
    }
    const u16* sA = ldsA + cur * 4096;
    const u16* sB = ldsB + cur * 4096;
    f16x8 af[4], bf[4];
#pragma unroll
    for (int m = 0; m < 4; ++m)
      af[m] = *(const f16x8*)(sA + (wr * 64 + m * 16 + lo) * 32 + hi * 8);
#pragma unroll
    for (int n = 0; n < 4; ++n)
      bf[n] = *(const f16x8*)(sB + (wc * 64 + n * 16 + lo) * 32 + hi * 8);
#pragma unroll
    for (int m = 0; m < 4; ++m)
#pragma unroll
      for (int n = 0; n < 4; ++n)
        acc[m][n] = __builtin_amdgcn_mfma_f32_16x16x32_f16(af[m], bf[n], acc[m][n], 0, 0, 0);
    __syncthreads();
  }

  if (z < 2) {
    u16* C = (z == 0) ? qm : km;
#pragma unroll
    for (int m = 0; m < 4; ++m) {
      const int row0 = bm * 128 + wr * 64 + m * 16 + hi * 4;
#pragma unroll
      for (int n = 0; n < 4; ++n) {
        const int col = bn * 128 + wc * 64 + n * 16 + lo;
#pragma unroll
        for (int r = 0; r < 4; ++r)
          C[(size_t)(row0 + r) * 1024 + col] = f2h(acc[m][n][r]);
      }
    }
  } else {
    // V transposed: vt[((b*16+h)*64+d)*4096 + s]
#pragma unroll
    for (int m = 0; m < 4; ++m) {
      const int row0 = bm * 128 + wr * 64 + m * 16 + hi * 4;
      const int bb = row0 >> 12, s = row0 & 4095;
#pragma unroll
      for (int n = 0; n < 4; ++n) {
        const int col = bn * 128 + wc * 64 + n * 16 + lo;
        const int hh = col >> 6, d = col & 63;
        uint2 pk;
        pk.x = pk2(acc[m][n][0], acc[m][n][1]);
        pk.y = pk2(acc[m][n][2], acc[m][n][3]);
        *(uint2*)(vt + ((size_t)(bb * 16 + hh) * 64 + d) * 4096 + s) = pk;
      }
    }
  }
}

// ---------------- out GEMM: out(f32) = ares * woT^T ----------------
__global__ __launch_bounds__(256) void k_gemm_out(const u16* __restrict__ ah,
                                                  const u16* __restrict__ woT,
                                                  float* __restrict__ out) {
  __shared__ __align__(16) u16 ldsA[2 * 4096];
  __shared__ __align__(16) u16 ldsB[2 * 4096];
  const int bm = blockIdx.x, bn = blockIdx.y;
  const int tid = threadIdx.x;
  const int l = tid & 63, w = tid >> 6;
  const int wr = w >> 1, wc = w & 1;
  const int lo = l & 15, hi = l >> 4;
  const int lr = l >> 2, lp = l & 3;
  const u16* aSrc = ah + (size_t)(bm * 128 + w * 32 + lr) * 1024 + lp * 8;
  const u16* bSrc = woT + (size_t)(bn * 128 + w * 32 + lr) * 1024 + lp * 8;
  u16* dA = ldsA + (w * 32) * 32;
  u16* dB = ldsB + (w * 32) * 32;

  f32x4 acc[4][4];
#pragma unroll
  for (int m = 0; m < 4; ++m)
#pragma unroll
    for (int n = 0; n < 4; ++n) {
      f32x4 zv = {0.f, 0.f, 0.f, 0.f};
      acc[m][n] = zv;
    }

#pragma unroll
  for (int j = 0; j < 2; ++j) {
    gl_lds16(aSrc + j * 16 * 1024, dA + j * 16 * 32);
    gl_lds16(bSrc + j * 16 * 1024, dB + j * 16 * 32);
  }
  __syncthreads();

  for (int kt = 0; kt < 32; ++kt) {
    const int cur = kt & 1;
    if (kt + 1 < 32) {
      const int ko = (kt + 1) * 32;
#pragma unroll
      for (int j = 0; j < 2; ++j) {
        gl_lds16(aSrc + ko + j * 16 * 1024, dA + (cur ^ 1) * 4096 + j * 16 * 32);
        gl_lds16(bSrc + ko + j * 16 * 1024, dB + (cur ^ 1) * 4096 + j * 16 * 32);
      }
    }
    const u16* sA = ldsA + cur * 4096;
    const u16* sB = ldsB + cur * 4096;
    f16x8 af[4], bf[4];
#pragma unroll
    for (int m = 0; m < 4; ++m)
      af[m] = *(const f16x8*)(sA + (wr * 64 + m * 16 + lo) * 32 + hi * 8);
#pragma unroll
    for (int n = 0; n < 4; ++n)
      bf[n] = *(const f16x8*)(sB + (wc * 64 + n * 16 + lo) * 32 + hi * 8);
#pragma unroll
    for (int m = 0; m < 4; ++m)
#pragma unroll
      for (int n = 0; n < 4; ++n)
        acc[m][n] = __builtin_amdgcn_mfma_f32_16x16x32_f16(af[m], bf[n], acc[m][n], 0, 0, 0);
    __syncthreads();
  }
#pragma unroll
  for (int m = 0; m < 4; ++m) {
    const int row0 = bm * 128 + wr * 64 + m * 16 + hi * 4;
#pragma unroll
    for (int n = 0; n < 4; ++n) {
      const int col = bn * 128 + wc * 64 + n * 16 + lo;
#pragma unroll
      for (int r = 0; r < 4; ++r)
        out[(size_t)(row0 + r) * 1024 + col] = acc[m][n][r];
    }
  }
}

// ---------------- fused attention: R22 structure + XCD-affine block mapping ----------------
// flat grid 2048; xcd = id&7 (dispatch round-robin); all 64 qt-blocks of one (b,h)
// land on ONE XCD so K/V tiles stay L2-resident (4 pairs x ~1MB = 4MB = L2 size).
// reg-staged dbuf, 1 barrier/tile, shuffle-free softmax (no-max + MFMA row-sum).
__global__ __launch_bounds__(256) void k_attn(const u16* __restrict__ qm,
                                              const u16* __restrict__ km,
                                              const u16* __restrict__ vt,
                                              u16* __restrict__ ares) {
  __shared__ __align__(16) u16 ldsK[2][64 * 64];
  __shared__ __align__(16) u16 ldsV[2][64 * 64];
  __shared__ __align__(16) u16 ldsP[4][16 * 64];
  const int id = blockIdx.x;
  const int xcd = id & 7, slot = id >> 3;       // 256 slots per XCD
  const int pair = xcd * 4 + (slot >> 6);       // 32 (h,b) pairs, 4 per XCD
  const int qslot = slot & 63;
  const int h = pair & 15, b = pair >> 4;
  const int qt = (qslot & ~15) | (15 - (qslot & 15));  // heavy-first within pair
  const int tid = threadIdx.x, l = tid & 63, w = tid >> 6;
  const int lo = l & 15, hi = l >> 4;
  const int sr = l >> 3, sp = l & 7;

  const int qrow = b * 4096 + qt * 64 + w * 16 + lo;
  f16x8 qf[2];
  qf[0] = *(const f16x8*)(qm + (size_t)qrow * 1024 + h * 64 + hi * 8);
  qf[1] = *(const f16x8*)(qm + (size_t)qrow * 1024 + h * 64 + 32 + hi * 8);
  const f16t qs = (f16t)0.18033688f;  // 0.125 * log2(e) folded into q
  qf[0] *= qs;
  qf[1] *= qs;

  const f16t one = (f16t)1.0f;
  const f16x8 ones = {one, one, one, one, one, one, one, one};

  f32x4 O[4], OL[4], L4;
#pragma unroll
  for (int n = 0; n < 4; ++n) {
    f32x4 zv = {0.f, 0.f, 0.f, 0.f};
    O[n] = zv; OL[n] = zv;
  }
  {
    f32x4 zv = {0.f, 0.f, 0.f, 0.f};
    L4 = zv;
  }

  u16* P = ldsP[w];
  const int nloc = (qt & 15) + 1;
  const int ntiles = nloc + 4;
  const int wbase = (qt >> 4) * 1024;

  // per-thread staging geometry (swizzle on source, linear LDS dest — rule #21)
  const int rt0 = w * 16 + sr;
  const int rt1 = w * 16 + 8 + sr;
  const int s0 = sp ^ (rt0 & 7);
  const int s1 = sp ^ (rt1 & 7);
  const int dOff0 = (w * 16 + 0) * 64 + l * 8;
  const int dOff1 = (w * 16 + 8) * 64 + l * 8;

  auto kseq_of = [&](int t) { return (t < nloc) ? (wbase + t * 64) : ((t - nloc) * 64); };

  uint4 rK0, rK1, rV0, rV1;
  auto stageLoad = [&](int t) {  // global -> regs (issued one tile early)
    const int kseq = kseq_of(t);
    rK0 = *(const uint4*)(km + (size_t)(b * 4096 + kseq + rt0) * 1024 + h * 64 + s0 * 8);
    rK1 = *(const uint4*)(km + (size_t)(b * 4096 + kseq + rt1) * 1024 + h * 64 + s1 * 8);
    rV0 = *(const uint4*)(vt + ((size_t)(b * 16 + h) * 64 + rt0) * 4096 + kseq + s0 * 8);
    rV1 = *(const uint4*)(vt + ((size_t)(b * 16 + h) * 64 + rt1) * 4096 + kseq + s1 * 8);
  };
  auto stageWrite = [&](int p) {  // regs -> LDS buf[p]
    *(uint4*)(ldsK[p] + dOff0) = rK0;
    *(uint4*)(ldsK[p] + dOff1) = rK1;
    *(uint4*)(ldsV[p] + dOff0) = rV0;
    *(uint4*)(ldsV[p] + dOff1) = rV1;
  };

  auto computeTile = [&](int p, bool diag) {
    const u16* sK = ldsK[p];
    const u16* sV = ldsV[p];
    f32x4 S[4];
#pragma unroll
    for (int n = 0; n < 4; ++n) {
      f32x4 zv = {0.f, 0.f, 0.f, 0.f};
      S[n] = zv;
      const int kk = n * 16 + lo;
#pragma unroll
      for (int c = 0; c < 2; ++c) {
        const int slot2 = hi + c * 4;
        f16x8 kf = *(const f16x8*)(sK + kk * 64 + ((slot2 ^ (kk & 7)) * 8));
        S[n] = __builtin_amdgcn_mfma_f32_16x16x32_f16(qf[c], kf, S[n], 0, 0, 0);
      }
    }
    // P = exp2(S) with fixed shift (no max, no shuffles); masked -> 0
#pragma unroll
    for (int n = 0; n < 4; ++n) {
      const int kk = n * 16 + lo;
#pragma unroll
      for (int r = 0; r < 4; ++r) {
        float v = S[n][r];
        if (diag && kk > (w * 16 + hi * 4 + r)) v = -1e30f;
        const int qr = hi * 4 + r;
        P[qr * 64 + ((((kk >> 3) ^ (qr & 7)) << 3) | (kk & 7))] = f2h(exp2f(v));
      }
    }
    // PV + row-sum via MFMA(ones)
#pragma unroll
    for (int kc = 0; kc < 2; ++kc) {
      const int slot2 = hi + kc * 4;
      f16x8 pa = *(const f16x8*)(P + lo * 64 + ((slot2 ^ (lo & 7)) * 8));
#pragma unroll
      for (int nn = 0; nn < 4; ++nn) {
        const int d = nn * 16 + lo;
        f16x8 vb = *(const f16x8*)(sV + d * 64 + ((slot2 ^ (d & 7)) * 8));
        O[nn] = __builtin_amdgcn_mfma_f32_16x16x32_f16(pa, vb, O[nn], 0, 0, 0);
      }
      L4 = __builtin_amdgcn_mfma_f32_16x16x32_f16(pa, ones, L4, 0, 0, 0);
    }
  };

  // prologue: tile 0 into buf0
  stageLoad(0);
  stageWrite(0);
  asm volatile("s_waitcnt lgkmcnt(0)" ::: "memory");
  asm volatile("s_barrier" ::: "memory");

  for (int t = 0; t < ntiles; ++t) {
    if (t + 1 < ntiles) stageLoad(t + 1);     // HBM latency hides under compute(t)
    computeTile(t & 1, t == nloc - 1);
    if (t == nloc - 1) {  // fold local branch; reset accumulators for global branch
      float inv[4];
#pragma unroll
      for (int r = 0; r < 4; ++r) inv[r] = 1.f / L4[r];
#pragma unroll
      for (int n = 0; n < 4; ++n) {
#pragma unroll
        for (int r = 0; r < 4; ++r) OL[n][r] = O[n][r] * inv[r];
        f32x4 zv = {0.f, 0.f, 0.f, 0.f};
        O[n] = zv;
      }
      f32x4 zv = {0.f, 0.f, 0.f, 0.f};
      L4 = zv;
    }
    if (t + 1 < ntiles) stageWrite((t + 1) & 1);  // buf^1's last reader was tile t-1 (done)
    asm volatile("s_waitcnt lgkmcnt(0)" ::: "memory");
    asm volatile("s_barrier" ::: "memory");       // ONE barrier per tile
  }

  float ig[4];
#pragma unroll
  for (int r = 0; r < 4; ++r) ig[r] = 1.f / L4[r];

  const int orow0 = b * 4096 + qt * 64 + w * 16 + hi * 4;
#pragma unroll
  for (int nn = 0; nn < 4; ++nn) {
    const int col = h * 64 + nn * 16 + lo;
#pragma unroll
    for (int r = 0; r < 4; ++r)
      ares[(size_t)(orow0 + r) * 1024 + col] = f2h(OL[nn][r] + O[nn][r] * ig[r]);
  }
}

extern "C" void kernel_launch(void* const* d_in, const int* in_sizes, int n_in,
                              void* d_out, int out_size, void* d_ws, size_t ws_size,
                              hipStream_t stream) {
  const int expect[9] = {8388608, 1048576, 1048576, 1048576, 1048576,
                         262144, 256, 256, 1};
  bool ok = (n_in == 9);
  if (ok)
    for (int i = 0; i < 9; ++i) ok = ok && (in_sizes[i] == expect[i]);
  if (!ok) {
    k_sentinel<<<(out_size + 255) / 256, 256, 0, stream>>>((float*)d_out, out_size, 3008.0f);
    return;
  }
  if (ws_size < (64ull << 20)) {
    k_sentinel<<<(out_size + 255) / 256, 256, 0, stream>>>((float*)d_out, out_size, 1000.0f);
    return;
  }

  const float* x  = (const float*)d_in[0];
  const float* wq = (const float*)d_in[1];
  const float* wk = (const float*)d_in[2];
  const float* wv = (const float*)d_in[3];
  const float* wo = (const float*)d_in[4];

  // ws layout (f16): wT 8MB | qm(/ares alias) 16MB | km 16MB | vt 16MB = 56MB
  // xh (16MB f16) lives in d_out (32MB f32 region, dead until k_gemm_out overwrites it)
  uint8_t* ws = (uint8_t*)d_ws;
  u16* wT = (u16*)ws;
  u16* qm = (u16*)(ws + (8ull << 20));
  u16* km = (u16*)(ws + (24ull << 20));
  u16* vt = (u16*)(ws + (40ull << 20));
  u16* ares = qm;           // block-exclusive read->write region in k_attn (safe)
  u16* xh = (u16*)d_out;    // scratch: overwritten by k_gemm_out at the end

  k_cvt_x<<<8192, 256, 0, stream>>>(x, xh, 2097152);
  k_cvt_w<<<dim3(32, 32, 4), dim3(32, 8), 0, stream>>>(wq, wk, wv, wo, wT);
  k_gemm_qkv<<<dim3(64, 8, 3), 256, 0, stream>>>(xh, wT, qm, km, vt);
  k_attn<<<2048, 256, 0, stream>>>(qm, km, vt, ares);
  k_gemm_out<<<dim3(64, 8), 256, 0, stream>>>(ares, wT + (3ull << 20), (float*)d_out);
}

// Round 27
// 193.931 us; speedup vs baseline: 2.7131x; 1.0007x over previous
//
#include <hip/hip_runtime.h>
#include <cstdint>

typedef unsigned short u16;
typedef _Float16 f16t;
typedef __attribute__((ext_vector_type(8))) _Float16 f16x8;
typedef __attribute__((ext_vector_type(4))) float f32x4;

__device__ __forceinline__ u16 f2h(float f) {
  f16t h = (f16t)f;
  return __builtin_bit_cast(u16, h);
}
__device__ __forceinline__ uint32_t pk2(float a, float b) {
  return (uint32_t)f2h(a) | ((uint32_t)f2h(b) << 16);
}
__device__ __forceinline__ void gl_lds16(const void* g, void* l) {
  __builtin_amdgcn_global_load_lds(
      (__attribute__((address_space(1))) const void*)g,
      (__attribute__((address_space(3))) void*)l, 16, 0, 0);
}

__global__ __launch_bounds__(256) void k_sentinel(float* out, int n, float val) {
  int i = blockIdx.x * 256 + threadIdx.x;
  if (i < n) out[i] = val;
}

// ---------------- x pre-pass: xh = (f16) x ----------------
__global__ __launch_bounds__(256) void k_cvt_x(const float* __restrict__ x,
                                               u16* __restrict__ xh, int n4) {
  int i = blockIdx.x * 256 + threadIdx.x;
  if (i >= n4) return;
  const float4 v = ((const float4*)x)[i];
  uint2 pk;
  pk.x = pk2(v.x, v.y);
  pk.y = pk2(v.z, v.w);
  ((uint2*)xh)[i] = pk;
}

// ---------------- weight pre-pass: wT[n][k] = (f16) W[k][n], 4 weights ----------------
__global__ __launch_bounds__(256) void k_cvt_w(const float* __restrict__ wq,
                                               const float* __restrict__ wk,
                                               const float* __restrict__ wv,
                                               const float* __restrict__ wo,
                                               u16* __restrict__ wT) {
  const float* W = blockIdx.z == 0 ? wq : blockIdx.z == 1 ? wk
                   : blockIdx.z == 2 ? wv : wo;
  u16* out = wT + (size_t)blockIdx.z * 1024 * 1024;
  __shared__ float t[32][33];
  const int tx = threadIdx.x, ty = threadIdx.y;
  const int bx = blockIdx.x, by = blockIdx.y;
#pragma unroll
  for (int i = 0; i < 4; ++i)
    t[ty + i * 8][tx] = W[(size_t)(by * 32 + ty + i * 8) * 1024 + bx * 32 + tx];
  __syncthreads();
#pragma unroll
  for (int i = 0; i < 4; ++i)
    out[(size_t)(bx * 32 + ty + i * 8) * 1024 + by * 32 + tx] = f2h(t[tx][ty + i * 8]);
}

// ---------------- QKV GEMM: C = xh[M,1024](f16) * wT[N,1024](f16)^T ----------------
__global__ __launch_bounds__(256) void k_gemm_qkv(const u16* __restrict__ xh,
                                                  const u16* __restrict__ wT,
                                                  u16* __restrict__ qm,
                                                  u16* __restrict__ km,
                                                  u16* __restrict__ vt) {
  __shared__ __align__(16) u16 ldsA[2 * 4096];
  __shared__ __align__(16) u16 ldsB[2 * 4096];
  const int bm = blockIdx.x, bn = blockIdx.y, z = blockIdx.z;
  const u16* BT = wT + (size_t)z * 1024 * 1024;
  const int tid = threadIdx.x;
  const int l = tid & 63, w = tid >> 6;
  const int wr = w >> 1, wc = w & 1;
  const int lo = l & 15, hi = l >> 4;
  const int lr = l >> 2, lp = l & 3;
  const u16* aSrc = xh + (size_t)(bm * 128 + w * 32 + lr) * 1024 + lp * 8;
  const u16* bSrc = BT + (size_t)(bn * 128 + w * 32 + lr) * 1024 + lp * 8;
  u16* dA = ldsA + (w * 32) * 32;
  u16* dB = ldsB + (w * 32) * 32;

  f32x4 acc[4][4];
#pragma unroll
  for (int m = 0; m < 4; ++m)
#pragma unroll
    for (int n = 0; n < 4; ++n) {
      f32x4 zv = {0.f, 0.f, 0.f, 0.f};
      acc[m][n] = zv;
    }

#pragma unroll
  for (int j = 0; j < 2; ++j) {
    gl_lds16(aSrc + j * 16 * 1024, dA + j * 16 * 32);
    gl_lds16(bSrc + j * 16 * 1024, dB + j * 16 * 32);
  }
  __syncthreads();

  for (int kt = 0; kt < 32; ++kt) {
    const int cur = kt & 1;
    if (kt + 1 < 32) {
      const int ko = (kt + 1) * 32;
#pragma unroll
      for (int j = 0; j < 2; ++j) {
        gl_lds16(aSrc + ko + j * 16 * 1024, dA + (cur ^ 1) * 4096 + j * 16 * 32);
        gl_lds16(bSrc + ko + j * 16 * 1024, dB + (cur ^ 1) * 4096 + j * 16 * 32);
      }
    }
    const u16* sA = ldsA + cur * 4096;
    const u16* sB = ldsB + cur * 4096;
    f16x8 af[4], bf[4];
#pragma unroll
    for (int m = 0; m < 4; ++m)
      af[m] = *(const f16x8*)(sA + (wr * 64 + m * 16 + lo) * 32 + hi * 8);
#pragma unroll
    for (int n = 0; n < 4; ++n)
      bf[n] = *(const f16x8*)(sB + (wc * 64 + n * 16 + lo) * 32 + hi * 8);
#pragma unroll
    for (int m = 0; m < 4; ++m)
#pragma unroll
      for (int n = 0; n < 4; ++n)
        acc[m][n] = __builtin_amdgcn_mfma_f32_16x16x32_f16(af[m], bf[n], acc[m][n], 0, 0, 0);
    __syncthreads();
  }

  if (z < 2) {
    u16* C = (z == 0) ? qm : km;
#pragma unroll
    for (int m = 0; m < 4; ++m) {
      const int row0 = bm * 128 + wr * 64 + m * 16 + hi * 4;
#pragma unroll
      for (int n = 0; n < 4; ++n) {
        const int col = bn * 128 + wc * 64 + n * 16 + lo;
#pragma unroll
        for (int r = 0; r < 4; ++r)
          C[(size_t)(row0 + r) * 1024 + col] = f2h(acc[m][n][r]);
      }
    }
  } else {
    // V transposed: vt[((b*16+h)*64+d)*4096 + s]
#pragma unroll
    for (int m = 0; m < 4; ++m) {
      const int row0 = bm * 128 + wr * 64 + m * 16 + hi * 4;
      const int bb = row0 >> 12, s = row0 & 4095;
#pragma unroll
      for (int n = 0; n < 4; ++n) {
        const int col = bn * 128 + wc * 64 + n * 16 + lo;
        const int hh = col >> 6, d = col & 63;
        uint2 pk;
        pk.x = pk2(acc[m][n][0], acc[m][n][1]);
        pk.y = pk2(acc[m][n][2], acc[m][n][3]);
        *(uint2*)(vt + ((size_t)(bb * 16 + hh) * 64 + d) * 4096 + s) = pk;
      }
    }
  }
}

// ---------------- out GEMM: out(f32) = ares * woT^T ----------------
__global__ __launch_bounds__(256) void k_gemm_out(const u16* __restrict__ ah,
                                                  const u16* __restrict__ woT,
                                                  float* __restrict__ out) {
  __shared__ __align__(16) u16 ldsA[2 * 4096];
  __shared__ __align__(16) u16 ldsB[2 * 4096];
  const int bm = blockIdx.x, bn = blockIdx.y;
  const int tid = threadIdx.x;
  const int l = tid & 63, w = tid >> 6;
  const int wr = w >> 1, wc = w & 1;
  const int lo = l & 15, hi = l >> 4;
  const int lr = l >> 2, lp = l & 3;
  const u16* aSrc = ah + (size_t)(bm * 128 + w * 32 + lr) * 1024 + lp * 8;
  const u16* bSrc = woT + (size_t)(bn * 128 + w * 32 + lr) * 1024 + lp * 8;
  u16* dA = ldsA + (w * 32) * 32;
  u16* dB = ldsB + (w * 32) * 32;

  f32x4 acc[4][4];
#pragma unroll
  for (int m = 0; m < 4; ++m)
#pragma unroll
    for (int n = 0; n < 4; ++n) {
      f32x4 zv = {0.f, 0.f, 0.f, 0.f};
      acc[m][n] = zv;
    }

#pragma unroll
  for (int j = 0; j < 2; ++j) {
    gl_lds16(aSrc + j * 16 * 1024, dA + j * 16 * 32);
    gl_lds16(bSrc + j * 16 * 1024, dB + j * 16 * 32);
  }
  __syncthreads();

  for (int kt = 0; kt < 32; ++kt) {
    const int cur = kt & 1;
    if (kt + 1 < 32) {
      const int ko = (kt + 1) * 32;
#pragma unroll
      for (int j = 0; j < 2; ++j) {
        gl_lds16(aSrc + ko + j * 16 * 1024, dA + (cur ^ 1) * 4096 + j * 16 * 32);
        gl_lds16(bSrc + ko + j * 16 * 1024, dB + (cur ^ 1) * 4096 + j * 16 * 32);
      }
    }
    const u16* sA = ldsA + cur * 4096;
    const u16* sB = ldsB + cur * 4096;
    f16x8 af[4], bf[4];
#pragma unroll
    for (int m = 0; m < 4; ++m)
      af[m] = *(const f16x8*)(sA + (wr * 64 + m * 16 + lo) * 32 + hi * 8);
#pragma unroll
    for (int n = 0; n < 4; ++n)
      bf[n] = *(const f16x8*)(sB + (wc * 64 + n * 16 + lo) * 32 + hi * 8);
#pragma unroll
    for (int m = 0; m < 4; ++m)
#pragma unroll
      for (int n = 0; n < 4; ++n)
        acc[m][n] = __builtin_amdgcn_mfma_f32_16x16x32_f16(af[m], bf[n], acc[m][n], 0, 0, 0);
    __syncthreads();
  }
#pragma unroll
  for (int m = 0; m < 4; ++m) {
    const int row0 = bm * 128 + wr * 64 + m * 16 + hi * 4;
#pragma unroll
    for (int n = 0; n < 4; ++n) {
      const int col = bn * 128 + wc * 64 + n * 16 + lo;
#pragma unroll
      for (int r = 0; r < 4; ++r)
        out[(size_t)(row0 + r) * 1024 + col] = acc[m][n][r];
    }
  }
}

// ---------------- fused attention: R24 structure + s_setprio on compute cluster ----------------
// flat grid 2048; XCD-affine mapping keeps each (b,h)'s K/V L2-resident.
// reg-staged dbuf, 1 barrier/tile, shuffle-free softmax (no-max + MFMA row-sum).
__global__ __launch_bounds__(256) void k_attn(const u16* __restrict__ qm,
                                              const u16* __restrict__ km,
                                              const u16* __restrict__ vt,
                                              u16* __restrict__ ares) {
  __shared__ __align__(16) u16 ldsK[2][64 * 64];
  __shared__ __align__(16) u16 ldsV[2][64 * 64];
  __shared__ __align__(16) u16 ldsP[4][16 * 64];
  const int id = blockIdx.x;
  const int xcd = id & 7, slot = id >> 3;       // 256 slots per XCD
  const int pair = xcd * 4 + (slot >> 6);       // 32 (h,b) pairs, 4 per XCD
  const int qslot = slot & 63;
  const int h = pair & 15, b = pair >> 4;
  const int qt = (qslot & ~15) | (15 - (qslot & 15));  // heavy-first within pair
  const int tid = threadIdx.x, l = tid & 63, w = tid >> 6;
  const int lo = l & 15, hi = l >> 4;
  const int sr = l >> 3, sp = l & 7;

  const int qrow = b * 4096 + qt * 64 + w * 16 + lo;
  f16x8 qf[2];
  qf[0] = *(const f16x8*)(qm + (size_t)qrow * 1024 + h * 64 + hi * 8);
  qf[1] = *(const f16x8*)(qm + (size_t)qrow * 1024 + h * 64 + 32 + hi * 8);
  const f16t qs = (f16t)0.18033688f;  // 0.125 * log2(e) folded into q
  qf[0] *= qs;
  qf[1] *= qs;

  const f16t one = (f16t)1.0f;
  const f16x8 ones = {one, one, one, one, one, one, one, one};

  f32x4 O[4], OL[4], L4;
#pragma unroll
  for (int n = 0; n < 4; ++n) {
    f32x4 zv = {0.f, 0.f, 0.f, 0.f};
    O[n] = zv; OL[n] = zv;
  }
  {
    f32x4 zv = {0.f, 0.f, 0.f, 0.f};
    L4 = zv;
  }

  u16* P = ldsP[w];
  const int nloc = (qt & 15) + 1;
  const int ntiles = nloc + 4;
  const int wbase = (qt >> 4) * 1024;

  // per-thread staging geometry (swizzle on source, linear LDS dest — rule #21)
  const int rt0 = w * 16 + sr;
  const int rt1 = w * 16 + 8 + sr;
  const int s0 = sp ^ (rt0 & 7);
  const int s1 = sp ^ (rt1 & 7);
  const int dOff0 = (w * 16 + 0) * 64 + l * 8;
  const int dOff1 = (w * 16 + 8) * 64 + l * 8;

  auto kseq_of = [&](int t) { return (t < nloc) ? (wbase + t * 64) : ((t - nloc) * 64); };

  uint4 rK0, rK1, rV0, rV1;
  auto stageLoad = [&](int t) {  // global -> regs (issued one tile early)
    const int kseq = kseq_of(t);
    rK0 = *(const uint4*)(km + (size_t)(b * 4096 + kseq + rt0) * 1024 + h * 64 + s0 * 8);
    rK1 = *(const uint4*)(km + (size_t)(b * 4096 + kseq + rt1) * 1024 + h * 64 + s1 * 8);
    rV0 = *(const uint4*)(vt + ((size_t)(b * 16 + h) * 64 + rt0) * 4096 + kseq + s0 * 8);
    rV1 = *(const uint4*)(vt + ((size_t)(b * 16 + h) * 64 + rt1) * 4096 + kseq + s1 * 8);
  };
  auto stageWrite = [&](int p) {  // regs -> LDS buf[p]
    *(uint4*)(ldsK[p] + dOff0) = rK0;
    *(uint4*)(ldsK[p] + dOff1) = rK1;
    *(uint4*)(ldsV[p] + dOff0) = rV0;
    *(uint4*)(ldsV[p] + dOff1) = rV1;
  };

  auto computeTile = [&](int p, bool diag) {
    const u16* sK = ldsK[p];
    const u16* sV = ldsV[p];
    __builtin_amdgcn_s_setprio(1);  // T5: favor this wave through the MFMA cluster
    f32x4 S[4];
#pragma unroll
    for (int n = 0; n < 4; ++n) {
      f32x4 zv = {0.f, 0.f, 0.f, 0.f};
      S[n] = zv;
      const int kk = n * 16 + lo;
#pragma unroll
      for (int c = 0; c < 2; ++c) {
        const int slot2 = hi + c * 4;
        f16x8 kf = *(const f16x8*)(sK + kk * 64 + ((slot2 ^ (kk & 7)) * 8));
        S[n] = __builtin_amdgcn_mfma_f32_16x16x32_f16(qf[c], kf, S[n], 0, 0, 0);
      }
    }
    // P = exp2(S) with fixed shift (no max, no shuffles); masked -> 0
#pragma unroll
    for (int n = 0; n < 4; ++n) {
      const int kk = n * 16 + lo;
#pragma unroll
      for (int r = 0; r < 4; ++r) {
        float v = S[n][r];
        if (diag && kk > (w * 16 + hi * 4 + r)) v = -1e30f;
        const int qr = hi * 4 + r;
        P[qr * 64 + ((((kk >> 3) ^ (qr & 7)) << 3) | (kk & 7))] = f2h(exp2f(v));
      }
    }
    // PV + row-sum via MFMA(ones)
#pragma unroll
    for (int kc = 0; kc < 2; ++kc) {
      const int slot2 = hi + kc * 4;
      f16x8 pa = *(const f16x8*)(P + lo * 64 + ((slot2 ^ (lo & 7)) * 8));
#pragma unroll
      for (int nn = 0; nn < 4; ++nn) {
        const int d = nn * 16 + lo;
        f16x8 vb = *(const f16x8*)(sV + d * 64 + ((slot2 ^ (d & 7)) * 8));
        O[nn] = __builtin_amdgcn_mfma_f32_16x16x32_f16(pa, vb, O[nn], 0, 0, 0);
      }
      L4 = __builtin_amdgcn_mfma_f32_16x16x32_f16(pa, ones, L4, 0, 0, 0);
    }
    __builtin_amdgcn_s_setprio(0);
  };

  // prologue: tile 0 into buf0
  stageLoad(0);
  stageWrite(0);
  asm volatile("s_waitcnt lgkmcnt(0)" ::: "memory");
  asm volatile("s_barrier" ::: "memory");

  for (int t = 0; t < ntiles; ++t) {
    if (t + 1 < ntiles) stageLoad(t + 1);     // HBM latency hides under compute(t)
    computeTile(t & 1, t == nloc - 1);
    if (t == nloc - 1) {  // fold local branch; reset accumulators for global branch
      float inv[4];
#pragma unroll
      for (int r = 0; r < 4; ++r) inv[r] = 1.f / L4[r];
#pragma unroll
      for (int n = 0; n < 4; ++n) {
#pragma unroll
        for (int r = 0; r < 4; ++r) OL[n][r] = O[n][r] * inv[r];
        f32x4 zv = {0.f, 0.f, 0.f, 0.f};
        O[n] = zv;
      }
      f32x4 zv = {0.f, 0.f, 0.f, 0.f};
      L4 = zv;
    }
    if (t + 1 < ntiles) stageWrite((t + 1) & 1);  // buf^1's last reader was tile t-1 (done)
    asm volatile("s_waitcnt lgkmcnt(0)" ::: "memory");
    asm volatile("s_barrier" ::: "memory");       // ONE barrier per tile
  }

  float ig[4];
#pragma unroll
  for (int r = 0; r < 4; ++r) ig[r] = 1.f / L4[r];

  const int orow0 = b * 4096 + qt * 64 + w * 16 + hi * 4;
#pragma unroll
  for (int nn = 0; nn < 4; ++nn) {
    const int col = h * 64 + nn * 16 + lo;
#pragma unroll
    for (int r = 0; r < 4; ++r)
      ares[(size_t)(orow0 + r) * 1024 + col] = f2h(OL[nn][r] + O[nn][r] * ig[r]);
  }
}

extern "C" void kernel_launch(void* const* d_in, const int* in_sizes, int n_in,
                              void* d_out, int out_size, void* d_ws, size_t ws_size,
                              hipStream_t stream) {
  const int expect[9] = {8388608, 1048576, 1048576, 1048576, 1048576,
                         262144, 256, 256, 1};
  bool ok = (n_in == 9);
  if (ok)
    for (int i = 0; i < 9; ++i) ok = ok && (in_sizes[i] == expect[i]);
  if (!ok) {
    k_sentinel<<<(out_size + 255) / 256, 256, 0, stream>>>((float*)d_out, out_size, 3008.0f);
    return;
  }
  if (ws_size < (64ull << 20)) {
    k_sentinel<<<(out_size + 255) / 256, 256, 0, stream>>>((float*)d_out, out_size, 1000.0f);
    return;
  }

  const float* x  = (const float*)d_in[0];
  const float* wq = (const float*)d_in[1];
  const float* wk = (const float*)d_in[2];
  const float* wv = (const float*)d_in[3];
  const float* wo = (const float*)d_in[4];

  // ws layout (f16): wT 8MB | qm(/ares alias) 16MB | km 16MB | vt 16MB = 56MB
  // xh (16MB f16) lives in d_out (32MB f32 region, dead until k_gemm_out overwrites it)
  uint8_t* ws = (uint8_t*)d_ws;
  u16* wT = (u16*)ws;
  u16* qm = (u16*)(ws + (8ull << 20));
  u16* km = (u16*)(ws + (24ull << 20));
  u16* vt = (u16*)(ws + (40ull << 20));
  u16* ares = qm;           // block-exclusive read->write region in k_attn (safe)
  u16* xh = (u16*)d_out;    // scratch: overwritten by k_gemm_out at the end

  k_cvt_x<<<8192, 256, 0, stream>>>(x, xh, 2097152);
  k_cvt_w<<<dim3(32, 32, 4), dim3(32, 8), 0, stream>>>(wq, wk, wv, wo, wT);
  k_gemm_qkv<<<dim3(64, 8, 3), 256, 0, stream>>>(xh, wT, qm, km, vt);
  k_attn<<<2048, 256, 0, stream>>>(qm, km, vt, ares);
  k_gemm_out<<<dim3(64, 8), 256, 0, stream>>>(ares, wT + (3ull << 20), (float*)d_out);
}